// Round 1
// baseline (198.350 us; speedup 1.0000x reference)
//
#include <hip/hip_runtime.h>
#include <hip/hip_bf16.h>

#define IM 1024
#define NSEG 128
#define EPSF 1e-10f

// ws layout (floats):
//   [0]  min bits (uint), [1] max bits (uint), [2] bf16 flag (uint)
//   [64 .. 64+128*16)   per-segment constants, 16 floats each (16B aligned)
//   [4096 .. 4096+1M)   fp32 template (path A only) -> byte offset 16384
#define WS_CONST_F 64
#define WS_TMPL_F 4096

__global__ void k_init_consts(const void* xs_raw, const void* ys_raw, float* ws) {
    __shared__ float sx[NSEG + 1], sy[NSEG + 1];
    __shared__ int sflag;
    unsigned* wsu = (unsigned*)ws;
    int t = threadIdx.x;
    if (t == 0) {
        // dtype detect: bf16 values must all be plausible coordinates
        const unsigned short* ux = (const unsigned short*)xs_raw;
        const unsigned short* uy = (const unsigned short*)ys_raw;
        bool plaus = true;
        for (int i = 0; i <= NSEG; ++i) {
            float fx = __uint_as_float(((unsigned)ux[i]) << 16);
            float fy = __uint_as_float(((unsigned)uy[i]) << 16);
            plaus = plaus && (fx >= 0.0f) && (fx <= 1024.0f)
                          && (fy >= 0.0f) && (fy <= 1024.0f);
        }
        sflag = plaus ? 1 : 0;
        wsu[0] = 0x7F800000u;  // running min init = +inf
        wsu[1] = 0u;           // running max init = 0 (template >= 0)
        wsu[2] = plaus ? 1u : 0u;
    }
    __syncthreads();
    int flag = sflag;
    if (t <= NSEG) {
        float x, y;
        if (flag) {
            x = __uint_as_float(((unsigned)((const unsigned short*)xs_raw)[t]) << 16);
            y = __uint_as_float(((unsigned)((const unsigned short*)ys_raw)[t]) << 16);
        } else {
            x = ((const float*)xs_raw)[t];
            y = ((const float*)ys_raw)[t];
        }
        sx[t] = x; sy[t] = y;
    }
    __syncthreads();
    if (t < NSEG) {
        float x0 = sx[t], y0 = sy[t], x1 = sx[t + 1], y1 = sy[t + 1];
        float dx = x1 - x0, dy = y1 - y0;
        float dx2 = dx * dx;
        float d = dx2 + dy * dy;
        float inv_d = 1.0f / (d + EPSF);
        float cross = y0 * x1 - x0 * y1;
        float a = dx * dy;
        float b = -dy * cross;
        bool vert = (x0 == x1);
        float slope = vert ? 0.0f : (dy / (dx + EPSF));
        float icpt  = vert ? 0.0f : (cross / (dx + EPSF));
        float vertc = vert ? 1.0f : 0.0f;
        float* c = ws + WS_CONST_F + t * 16;
        c[0] = dx2;  c[1] = inv_d; c[2] = a;     c[3] = b;
        c[4] = slope; c[5] = icpt; c[6] = vertc; c[7] = 0.0f;
        c[8] = fminf(x0, x1); c[9]  = fmaxf(x0, x1);
        c[10] = fminf(y0, y1); c[11] = fmaxf(y0, y1);
    }
}

// Accumulate the 128-segment distance field for 4 pixels of one row.
// Branchless: vert segments stored with slope=icpt=0, vertc=1 so
// y_gen = yp; xc clamps to [x1,x1] = x1 exactly.
__device__ __forceinline__ void render_row(const float* __restrict__ cst,
                                           float yp, float xp0, float acc[4]) {
    acc[0] = 0.0f; acc[1] = 0.0f; acc[2] = 0.0f; acc[3] = 0.0f;
    const float* c = cst;
    for (int s = 0; s < NSEG; ++s, c += 16) {
        float dx2 = c[0], inv_d = c[1], a = c[2], b = c[3];
        float slope = c[4], icpt = c[5], vertc = c[6];
        float xmn = c[8], xmx = c[9], ymn = c[10], ymx = c[11];
        float nbase = a * yp + b;
        float ybase = vertc * yp + icpt;  // = yp for vert, icpt otherwise
#pragma unroll
        for (int k = 0; k < 4; ++k) {
            float xp = xp0 + 256.0f * (float)k;
            float n  = nbase + dx2 * xp;
            float xg = n * inv_d;
            float yg = slope * xg + ybase;
            float xc = fminf(fmaxf(xg, xmn), xmx);
            float yc = fminf(fmaxf(yg, ymn), ymx);
            float ddx = xp - xc;
            float ddy = yp - yc;
            float d2 = ddx * ddx + (ddy * ddy + EPSF);
            acc[k] += __builtin_amdgcn_sqrtf(d2);
        }
    }
}

template <bool STORE>
__global__ __launch_bounds__(256) void k_template(const float* __restrict__ cst,
                                                  float* __restrict__ tmpl,
                                                  unsigned* wsu) {
    int y = blockIdx.x;
    int tx = threadIdx.x;
    float acc[4];
    render_row(cst, (float)y, (float)tx, acc);

    float tmn = fminf(fminf(acc[0], acc[1]), fminf(acc[2], acc[3]));
    float tmx = fmaxf(fmaxf(acc[0], acc[1]), fmaxf(acc[2], acc[3]));
    for (int off = 32; off > 0; off >>= 1) {
        tmn = fminf(tmn, __shfl_down(tmn, off));
        tmx = fmaxf(tmx, __shfl_down(tmx, off));
    }
    if ((tx & 63) == 0) {
        atomicMin(wsu + 0, __float_as_uint(tmn));
        atomicMax(wsu + 1, __float_as_uint(tmx));
    }
    if (STORE) {
#pragma unroll
        for (int k = 0; k < 4; ++k)
            tmpl[y * IM + tx + 256 * k] = acc[k];
    }
}

__global__ __launch_bounds__(256) void k_norm_stored(const float* __restrict__ tmpl,
                                                     const unsigned* __restrict__ wsu,
                                                     void* out) {
    float tmin = __uint_as_float(wsu[0]);
    float scale = 1.0f / (__uint_as_float(wsu[1]) - tmin);
    int flag = (int)wsu[2];
    int idx = (blockIdx.x * 256 + threadIdx.x) * 4;
    float4 t = *(const float4*)(tmpl + idx);
    float r0 = (t.x - tmin) * scale;
    float r1 = (t.y - tmin) * scale;
    float r2 = (t.z - tmin) * scale;
    float r3 = (t.w - tmin) * scale;
    if (flag) {
        __hip_bfloat16 h0 = __float2bfloat16(r0);
        __hip_bfloat16 h1 = __float2bfloat16(r1);
        __hip_bfloat16 h2 = __float2bfloat16(r2);
        __hip_bfloat16 h3 = __float2bfloat16(r3);
        ushort4 p;
        p.x = *(unsigned short*)&h0; p.y = *(unsigned short*)&h1;
        p.z = *(unsigned short*)&h2; p.w = *(unsigned short*)&h3;
        *(ushort4*)((unsigned short*)out + idx) = p;
    } else {
        *(float4*)((float*)out + idx) = make_float4(r0, r1, r2, r3);
    }
}

// Fallback if ws is too small to hold the fp32 template: recompute.
__global__ __launch_bounds__(256) void k_norm_recompute(const float* __restrict__ cst,
                                                        const unsigned* __restrict__ wsu,
                                                        void* out) {
    float tmin = __uint_as_float(wsu[0]);
    float scale = 1.0f / (__uint_as_float(wsu[1]) - tmin);
    int flag = (int)wsu[2];
    int y = blockIdx.x;
    int tx = threadIdx.x;
    float acc[4];
    render_row(cst, (float)y, (float)tx, acc);
#pragma unroll
    for (int k = 0; k < 4; ++k) {
        float r = (acc[k] - tmin) * scale;
        int idx = y * IM + tx + 256 * k;
        if (flag) {
            __hip_bfloat16 h = __float2bfloat16(r);
            ((unsigned short*)out)[idx] = *(unsigned short*)&h;
        } else {
            ((float*)out)[idx] = r;
        }
    }
}

extern "C" void kernel_launch(void* const* d_in, const int* in_sizes, int n_in,
                              void* d_out, int out_size, void* d_ws, size_t ws_size,
                              hipStream_t stream) {
    const void* xs = d_in[0];
    const void* ys = d_in[1];
    float* wsf = (float*)d_ws;
    unsigned* wsu = (unsigned*)d_ws;
    const float* cst = wsf + WS_CONST_F;
    float* tmpl = wsf + WS_TMPL_F;
    bool pathA = ws_size >= (size_t)(WS_TMPL_F * 4) + (size_t)IM * IM * 4;

    hipLaunchKernelGGL(k_init_consts, dim3(1), dim3(256), 0, stream, xs, ys, wsf);
    if (pathA) {
        hipLaunchKernelGGL((k_template<true>), dim3(IM), dim3(256), 0, stream,
                           cst, tmpl, wsu);
        hipLaunchKernelGGL(k_norm_stored, dim3(IM), dim3(256), 0, stream,
                           tmpl, wsu, d_out);
    } else {
        hipLaunchKernelGGL((k_template<false>), dim3(IM), dim3(256), 0, stream,
                           cst, (float*)nullptr, wsu);
        hipLaunchKernelGGL(k_norm_recompute, dim3(IM), dim3(256), 0, stream,
                           cst, wsu, d_out);
    }
}

// Round 2
// 94.612 us; speedup vs baseline: 2.0965x; 2.0965x over previous
//
#include <hip/hip_runtime.h>
#include <hip/hip_bf16.h>

#define IM 1024
#define NSEG 128
#define EPSF 1e-10f

// ws layout (floats):
//   [0]            bf16 flag (uint)
//   [64 .. 1088)   per-row min  (1024)
//   [2048 .. 3072) per-row max  (1024)
//   [4096 .. +1M)  fp32 template (path A)
#define WS_FLAG 0
#define WS_BMIN 64
#define WS_BMAX 2048
#define WS_TMPL 4096

__device__ __forceinline__ float bf16_decode(unsigned short u) {
    return __uint_as_float(((unsigned)u) << 16);
}

// Fill per-segment constants into LDS; returns bf16 flag (block-uniform).
__device__ __forceinline__ int setup_consts(const void* xs_raw, const void* ys_raw,
                                            float4* cA, float2* cB,
                                            float* sx, float* sy, int* sflag) {
    int tx = threadIdx.x;
    if (tx == 0) *sflag = 1;
    __syncthreads();
    if (tx <= NSEG) {
        unsigned short ux = ((const unsigned short*)xs_raw)[tx];
        unsigned short uy = ((const unsigned short*)ys_raw)[tx];
        float fx = bf16_decode(ux), fy = bf16_decode(uy);
        bool plaus = (fx >= 0.0f) && (fx <= 1024.0f) && (fy >= 0.0f) && (fy <= 1024.0f);
        if (!plaus) atomicAnd(sflag, 0);
        sx[tx] = fx; sy[tx] = fy;
    }
    __syncthreads();
    int flag = *sflag;
    if (!flag && tx <= NSEG) {
        sx[tx] = ((const float*)xs_raw)[tx];
        sy[tx] = ((const float*)ys_raw)[tx];
    }
    __syncthreads();
    if (tx < NSEG) {
        float x0 = sx[tx], y0 = sy[tx], x1 = sx[tx + 1], y1 = sy[tx + 1];
        float dx = x1 - x0, dy = y1 - y0;
        float inv_d = 1.0f / (dx * dx + dy * dy + EPSF);
        float c0n = -(dx * x0 + dy * y0);
        cA[tx] = make_float4(dx, dy, x0, y0);
        cB[tx] = make_float2(inv_d, c0n);
    }
    __syncthreads();
    return flag;
}

// Accumulate 128-segment distance field for 4 pixels {tx, tx+256, tx+512, tx+768}.
__device__ __forceinline__ void render4(const float4* cA, const float2* cB,
                                        float yp, float xp0, float acc[4]) {
    float a0 = 0.f, a1 = 0.f, a2 = 0.f, a3 = 0.f;
    float x1p = xp0 + 256.f, x2p = xp0 + 512.f, x3p = xp0 + 768.f;
#pragma unroll 4
    for (int s = 0; s < NSEG; ++s) {
        float4 A = cA[s];
        float2 B = cB[s];
        float rb = fmaf(A.y, yp, B.y);  // dy*yp - (dx*x0 + dy*y0)
        {
            float t = fmaf(A.x, xp0, rb) * B.x;
            t = fminf(fmaxf(t, 0.0f), 1.0f);
            float xc = fmaf(t, A.x, A.z), yc = fmaf(t, A.y, A.w);
            float dx = xp0 - xc, dy = yp - yc;
            a0 += __builtin_amdgcn_sqrtf(fmaf(dx, dx, fmaf(dy, dy, EPSF)));
        }
        {
            float t = fmaf(A.x, x1p, rb) * B.x;
            t = fminf(fmaxf(t, 0.0f), 1.0f);
            float xc = fmaf(t, A.x, A.z), yc = fmaf(t, A.y, A.w);
            float dx = x1p - xc, dy = yp - yc;
            a1 += __builtin_amdgcn_sqrtf(fmaf(dx, dx, fmaf(dy, dy, EPSF)));
        }
        {
            float t = fmaf(A.x, x2p, rb) * B.x;
            t = fminf(fmaxf(t, 0.0f), 1.0f);
            float xc = fmaf(t, A.x, A.z), yc = fmaf(t, A.y, A.w);
            float dx = x2p - xc, dy = yp - yc;
            a2 += __builtin_amdgcn_sqrtf(fmaf(dx, dx, fmaf(dy, dy, EPSF)));
        }
        {
            float t = fmaf(A.x, x3p, rb) * B.x;
            t = fminf(fmaxf(t, 0.0f), 1.0f);
            float xc = fmaf(t, A.x, A.z), yc = fmaf(t, A.y, A.w);
            float dx = x3p - xc, dy = yp - yc;
            a3 += __builtin_amdgcn_sqrtf(fmaf(dx, dx, fmaf(dy, dy, EPSF)));
        }
    }
    acc[0] = a0; acc[1] = a1; acc[2] = a2; acc[3] = a3;
}

template <bool STORE>
__global__ __launch_bounds__(256) void k_render(const void* __restrict__ xs_raw,
                                                const void* __restrict__ ys_raw,
                                                float* __restrict__ ws) {
    __shared__ float4 cA[NSEG];
    __shared__ float2 cB[NSEG];
    __shared__ float sx[NSEG + 1], sy[NSEG + 1];
    __shared__ int sflag;
    __shared__ float swmn[4], swmx[4];

    int tx = threadIdx.x;
    int y = blockIdx.x;
    int flag = setup_consts(xs_raw, ys_raw, cA, cB, sx, sy, &sflag);

    float acc[4];
    render4(cA, cB, (float)y, (float)tx, acc);

    float tmn = fminf(fminf(acc[0], acc[1]), fminf(acc[2], acc[3]));
    float tmx = fmaxf(fmaxf(acc[0], acc[1]), fmaxf(acc[2], acc[3]));
    for (int off = 32; off > 0; off >>= 1) {
        tmn = fminf(tmn, __shfl_down(tmn, off));
        tmx = fmaxf(tmx, __shfl_down(tmx, off));
    }
    if ((tx & 63) == 0) { swmn[tx >> 6] = tmn; swmx[tx >> 6] = tmx; }
    __syncthreads();
    if (tx == 0) {
        float m = fminf(fminf(swmn[0], swmn[1]), fminf(swmn[2], swmn[3]));
        float M = fmaxf(fmaxf(swmx[0], swmx[1]), fmaxf(swmx[2], swmx[3]));
        ws[WS_BMIN + y] = m;
        ws[WS_BMAX + y] = M;
        if (y == 0) ((unsigned*)ws)[WS_FLAG] = (unsigned)flag;
    }
    if (STORE) {
        float* tmpl = ws + WS_TMPL + y * IM + tx;
        tmpl[0] = acc[0]; tmpl[256] = acc[1]; tmpl[512] = acc[2]; tmpl[768] = acc[3];
    }
}

__device__ __forceinline__ void global_minmax(const float* __restrict__ ws,
                                              float* swmn, float* swmx, float* sred,
                                              float& tmin, float& scale) {
    int tx = threadIdx.x;
    float mn = 1e30f, mx = -1e30f;
#pragma unroll
    for (int i = 0; i < 4; ++i) {
        mn = fminf(mn, ws[WS_BMIN + tx + 256 * i]);
        mx = fmaxf(mx, ws[WS_BMAX + tx + 256 * i]);
    }
    for (int off = 32; off > 0; off >>= 1) {
        mn = fminf(mn, __shfl_down(mn, off));
        mx = fmaxf(mx, __shfl_down(mx, off));
    }
    if ((tx & 63) == 0) { swmn[tx >> 6] = mn; swmx[tx >> 6] = mx; }
    __syncthreads();
    if (tx == 0) {
        float m = fminf(fminf(swmn[0], swmn[1]), fminf(swmn[2], swmn[3]));
        float M = fmaxf(fmaxf(swmx[0], swmx[1]), fmaxf(swmx[2], swmx[3]));
        sred[0] = m;
        sred[1] = 1.0f / (M - m);
    }
    __syncthreads();
    tmin = sred[0];
    scale = sred[1];
}

__global__ __launch_bounds__(256) void k_norm(const float* __restrict__ ws,
                                              void* __restrict__ out) {
    __shared__ float swmn[4], swmx[4], sred[2];
    float tmin, scale;
    global_minmax(ws, swmn, swmx, sred, tmin, scale);
    int flag = (int)((const unsigned*)ws)[WS_FLAG];
    int idx = (blockIdx.x * 256 + threadIdx.x) * 4;
    float4 t = *(const float4*)(ws + WS_TMPL + idx);
    float r0 = (t.x - tmin) * scale;
    float r1 = (t.y - tmin) * scale;
    float r2 = (t.z - tmin) * scale;
    float r3 = (t.w - tmin) * scale;
    if (flag) {
        __hip_bfloat16 h0 = __float2bfloat16(r0);
        __hip_bfloat16 h1 = __float2bfloat16(r1);
        __hip_bfloat16 h2 = __float2bfloat16(r2);
        __hip_bfloat16 h3 = __float2bfloat16(r3);
        ushort4 p;
        p.x = *(unsigned short*)&h0; p.y = *(unsigned short*)&h1;
        p.z = *(unsigned short*)&h2; p.w = *(unsigned short*)&h3;
        *(ushort4*)((unsigned short*)out + idx) = p;
    } else {
        *(float4*)((float*)out + idx) = make_float4(r0, r1, r2, r3);
    }
}

// Fallback when ws can't hold the template: recompute the row, then normalize.
__global__ __launch_bounds__(256) void k_norm_recompute(const void* __restrict__ xs_raw,
                                                        const void* __restrict__ ys_raw,
                                                        const float* __restrict__ ws,
                                                        void* __restrict__ out) {
    __shared__ float4 cA[NSEG];
    __shared__ float2 cB[NSEG];
    __shared__ float sx[NSEG + 1], sy[NSEG + 1];
    __shared__ int sflag;
    __shared__ float swmn[4], swmx[4], sred[2];

    int tx = threadIdx.x;
    int y = blockIdx.x;
    int flag = setup_consts(xs_raw, ys_raw, cA, cB, sx, sy, &sflag);
    float tmin, scale;
    global_minmax(ws, swmn, swmx, sred, tmin, scale);
    float acc[4];
    render4(cA, cB, (float)y, (float)tx, acc);
#pragma unroll
    for (int k = 0; k < 4; ++k) {
        float r = (acc[k] - tmin) * scale;
        int idx = y * IM + tx + 256 * k;
        if (flag) {
            __hip_bfloat16 h = __float2bfloat16(r);
            ((unsigned short*)out)[idx] = *(unsigned short*)&h;
        } else {
            ((float*)out)[idx] = r;
        }
    }
}

extern "C" void kernel_launch(void* const* d_in, const int* in_sizes, int n_in,
                              void* d_out, int out_size, void* d_ws, size_t ws_size,
                              hipStream_t stream) {
    const void* xs = d_in[0];
    const void* ys = d_in[1];
    float* wsf = (float*)d_ws;
    bool pathA = ws_size >= (size_t)(WS_TMPL + IM * IM) * sizeof(float);

    if (pathA) {
        hipLaunchKernelGGL((k_render<true>), dim3(IM), dim3(256), 0, stream, xs, ys, wsf);
        hipLaunchKernelGGL(k_norm, dim3(IM), dim3(256), 0, stream, wsf, d_out);
    } else {
        hipLaunchKernelGGL((k_render<false>), dim3(IM), dim3(256), 0, stream, xs, ys, wsf);
        hipLaunchKernelGGL(k_norm_recompute, dim3(IM), dim3(256), 0, stream,
                           xs, ys, wsf, d_out);
    }
}